// Round 4
// baseline (121.110 us; speedup 1.0000x reference)
//
#include <hip/hip_runtime.h>
#include <stdint.h>

#define N_ROWS   16384
#define IN_DIM   512
#define CB_DIM   16
#define CB_VOCAB 8192

// ---- K1 geometry
#define PREP_BLOCKS 128                          // 4 code-tiles each + P-frags
#define PROJ_BLOCKS 256                          // 64 rows each (4 row-tiles)

// ---- scan geometry
#define N_RT   (N_ROWS / 16)                     // 1024 row-tiles
#define N_CT   (CB_VOCAB / 16)                   // 512 code-tiles
#define CODEPARTS 32
#define CT_PER_PART (N_CT / CODEPARTS)           // 16
#define N_ROWGRP 64                              // 256 rows per rowgrp

// ---- workspace layout (bytes), ~3.3 MB
#define WS_OFF_AFA  0                            // A-frag [A1|A2]: 1 MB
#define WS_OFF_AFB  (1u << 20)                   // A-frag [A1|A3]: 1 MB
#define WS_OFF_BHH  (2u << 20)                   // B-frag [B1;B2]: 512 KB
#define WS_OFF_B31  ((2u << 20) + (512u << 10))  // B-frag [B3;B1]: 512 KB
#define WS_OFF_PART (3u << 20)                   // u64[16384]: 128 KB
#define WS_OFF_CNT  ((3u << 20) + (128u << 10))  // u32[64]
#define WS_OFF_PF   ((3u << 20) + (192u << 10))  // P-frags: 3 x 1024 x 16 B = 48 KB

typedef __attribute__((ext_vector_type(8))) short bf16x8;
typedef __attribute__((ext_vector_type(4))) float f32x4;

// monotone float -> uint32 key (order-preserving)
__device__ __forceinline__ unsigned fkey(float f) {
    unsigned u = __float_as_uint(f);
    return (u & 0x80000000u) ? ~u : (u | 0x80000000u);
}

// fp32 -> bf16 bits, round-to-nearest-even
__device__ __forceinline__ unsigned short f2bf(float f) {
    unsigned u = __float_as_uint(f);
    return (unsigned short)((u + 0x7FFFu + ((u >> 16) & 1u)) >> 16);
}
__device__ __forceinline__ float bf2f(unsigned short h) {
    return __uint_as_float(((unsigned)h) << 16);
}

// ---------------- K0: prep — zero part/cnt, CB B-frags, P B-frags ----------
// P-frag layout (for the proj MFMA): level L in {0,1,2}, chunk c in [0,16)
// covers real k in [c*32, c*32+32). Frag lane l: n = l&15 (output dim),
// k = c*32 + (l>>4)*8 + j. Stored Pf[L*1024 + c*64 + l] as bf16x8.
__global__ __launch_bounds__(256, 2)
void k_prep(const float* __restrict__ P, const float* __restrict__ CB,
            bf16x8* __restrict__ Bhh, bf16x8* __restrict__ B31,
            bf16x8* __restrict__ Pf,
            unsigned long long* __restrict__ part, unsigned* __restrict__ cnt) {
    const int pb   = blockIdx.x;
    const int wave = threadIdx.x >> 6;
    const int lane = threadIdx.x & 63;

    if (threadIdx.x < 128) part[pb * 128 + threadIdx.x] = 0ull;
    if (pb == 0 && threadIdx.x < 64) cnt[threadIdx.x] = 0u;

    // ---- CB B-frags (identical to previous prep path) ----
    {
        const int ct   = pb * 4 + wave;
        const int n    = lane & 15;
        const int quad = lane >> 4;
        const int kh   = (quad & 1) * 8;
        const int lvl  = quad >> 1;
        const int code = ct * 16 + n;

        const float4* b4 = (const float4*)(CB + (size_t)code * CB_DIM + kh);
        float4 a = b4[0], b = b4[1];
        float v[8] = {a.x, a.y, a.z, a.w, b.x, b.y, b.z, b.w};

        bf16x8 shh, s31;
#pragma unroll
        for (int j = 0; j < 8; ++j) {
            float f = v[j];
            unsigned short b1 = f2bf(f);  float r1 = f - bf2f(b1);
            unsigned short b2 = f2bf(r1); float r2 = r1 - bf2f(b2);
            unsigned short b3 = f2bf(r2);
            shh[j] = (short)(lvl ? b2 : b1);
            s31[j] = (short)(lvl ? b1 : b3);
        }
        Bhh[(size_t)ct * 64 + lane] = shh;
        B31[(size_t)ct * 64 + lane] = s31;
    }

    // ---- P B-frags: 1024 frag-lane slots, built by blocks 0..3 ----
    const int gslot = pb * 256 + threadIdx.x;
    if (gslot < 1024) {
        const int c  = gslot >> 6;
        const int l  = gslot & 63;
        const int n  = l & 15;
        const int kq = l >> 4;
        const int k0 = c * 32 + kq * 8;

        bf16x8 p1, p2, p3;
#pragma unroll
        for (int j = 0; j < 8; ++j) {
            float f = P[(size_t)(k0 + j) * CB_DIM + n];
            unsigned short b1 = f2bf(f);  float r1 = f - bf2f(b1);
            unsigned short b2 = f2bf(r1); float r2 = r1 - bf2f(b2);
            unsigned short b3 = f2bf(r2);
            p1[j] = (short)b1; p2[j] = (short)b2; p3[j] = (short)b3;
        }
        Pf[gslot]        = p1;
        Pf[1024 + gslot] = p2;
        Pf[2048 + gslot] = p3;
    }
}

// ---------------- K1: MFMA projection -> A-frags -----------------------------
// R3 post-mortem: the VALU+LDS proj was Ps-broadcast-bound (34 ds_read_b128
// per thread per chunk vs 128 FMAs, 8 barriers, 2 blocks/CU). proj IS
// matmul-shaped (K=512): do it on the MFMA pipe. 3-way bf16 split of x is an
// EXACT fp32 decomposition (3x8=24 mantissa bits); keeping i+j<=4 cross
// terms (6 MFMAs/chunk, 2 independent 3-chains) gives ~2^-24 relative error
// -- same class as the sim's established-passing split. No x-LDS, no
// barriers; x loads coalesced 32 B/lane with 4-deep prefetch (~64 KB in
// flight/CU vs ~9 KB BW*latency needed). Epilogue transposes the C-layout
// (col-per-lane) to the A-frag layout (row-per-lane) via a 1.25 KB
// wave-private LDS bounce (wave-synchronous: lgkmcnt(0)+sched_barrier, rule
// 18; [16][20] padding -> only 2-way bank aliasing = free).
// Floor: x read 32 MB -> 5.1 us; MFMA 0.8 us; split ~1.5 us (overlapped).
__global__ __launch_bounds__(256, 1)
void k_proj(const float* __restrict__ x, const bf16x8* __restrict__ Pf,
            bf16x8* __restrict__ AfragA, bf16x8* __restrict__ AfragB) {
    __shared__ float xpL[4][16][20];
    const int wave = threadIdx.x >> 6;
    const int lane = threadIdx.x & 63;
    const int rt   = blockIdx.x * 4 + wave;      // this wave's row-tile
    const int m    = lane & 15;                  // row within tile
    const int kq   = lane >> 4;                  // k-quad

    // lane's x addresses: row rt*16+m, 32 B at chunk c: bytes [c*128 + kq*32)
    const float4* xr =
        (const float4*)(x + (size_t)(rt * 16 + m) * IN_DIM) + kq * 2;

    f32x4 acc1 = {0.f, 0.f, 0.f, 0.f};
    f32x4 acc2 = {0.f, 0.f, 0.f, 0.f};

    float4 xf0[4], xf1[4];                       // 4-deep chunk prefetch
#pragma unroll
    for (int c = 0; c < 4; ++c) { xf0[c] = xr[c * 8]; xf1[c] = xr[c * 8 + 1]; }

#pragma unroll
    for (int c = 0; c < 16; ++c) {
        bf16x8 p1 = Pf[c * 64 + lane];           // L2-hot, lane-contiguous
        bf16x8 p2 = Pf[1024 + c * 64 + lane];
        bf16x8 p3 = Pf[2048 + c * 64 + lane];

        float4 xa = xf0[c & 3], xb = xf1[c & 3];
        if (c + 4 < 16) {
            xf0[c & 3] = xr[(c + 4) * 8];
            xf1[c & 3] = xr[(c + 4) * 8 + 1];
        }

        float xs[8] = {xa.x, xa.y, xa.z, xa.w, xb.x, xb.y, xb.z, xb.w};
        bf16x8 a1, a2, a3;
#pragma unroll
        for (int j = 0; j < 8; ++j) {
            float f = xs[j];
            unsigned short b1 = f2bf(f);  float r1 = f - bf2f(b1);
            unsigned short b2 = f2bf(r1); float r2 = r1 - bf2f(b2);
            unsigned short b3 = f2bf(r2);
            a1[j] = (short)b1; a2[j] = (short)b2; a3[j] = (short)b3;
        }

        // terms i+j<=4: (1,1)(2,1)(2,2) chain1; (1,2)(1,3)(3,1) chain2
        acc1 = __builtin_amdgcn_mfma_f32_16x16x32_bf16(a1, p1, acc1, 0, 0, 0);
        acc2 = __builtin_amdgcn_mfma_f32_16x16x32_bf16(a1, p2, acc2, 0, 0, 0);
        acc1 = __builtin_amdgcn_mfma_f32_16x16x32_bf16(a2, p1, acc1, 0, 0, 0);
        acc2 = __builtin_amdgcn_mfma_f32_16x16x32_bf16(a1, p3, acc2, 0, 0, 0);
        acc1 = __builtin_amdgcn_mfma_f32_16x16x32_bf16(a2, p2, acc1, 0, 0, 0);
        acc2 = __builtin_amdgcn_mfma_f32_16x16x32_bf16(a3, p1, acc2, 0, 0, 0);
    }

    // C layout: lane holds xp[row=(kq*4+r)][col=m] -> bounce through LDS to
    // the A-frag layout (lane = row m, dims per quad).
#pragma unroll
    for (int r = 0; r < 4; ++r)
        xpL[wave][kq * 4 + r][m] = acc1[r] + acc2[r];

    asm volatile("s_waitcnt lgkmcnt(0)" ::: "memory");
    __builtin_amdgcn_sched_barrier(0);

    const int kh  = (kq & 1) * 8;
    const int lvl = kq >> 1;
    bf16x8 sa, sb;
#pragma unroll
    for (int j = 0; j < 8; ++j) {
        float f = xpL[wave][m][kh + j];
        unsigned short b1 = f2bf(f);  float r1 = f - bf2f(b1);
        unsigned short b2 = f2bf(r1); float r2 = r1 - bf2f(b2);
        unsigned short b3 = f2bf(r2);
        sa[j] = (short)(lvl ? b2 : b1);
        sb[j] = (short)(lvl ? b3 : b1);
    }
    AfragA[(size_t)rt * 64 + lane] = sa;
    AfragB[(size_t)rt * 64 + lane] = sb;
}

// ---------------- K2: MFMA sim + argmax + last-block finalize ---------------
// UNCHANGED from R3 (keeps attribution clean). grid 2048 = 64 rowgrps x 32
// codeparts; wave = 4 row-tiles x 16 code-tiles; (256,4) -> 64 VGPR, no
// spill; 8 blocks/CU. 3 chained bf16 MFMAs per tile, SW-pipelined B loads.
__global__ __launch_bounds__(256, 4)
void k_scan(const bf16x8* __restrict__ AfragA, const bf16x8* __restrict__ AfragB,
            const bf16x8* __restrict__ Bhh, const bf16x8* __restrict__ B31,
            unsigned long long* __restrict__ part, unsigned* __restrict__ cnt,
            int* __restrict__ out) {
    __shared__ int s_done;
    const int codepart = blockIdx.x & (CODEPARTS - 1);
    const int rowgrp   = blockIdx.x >> 5;
    const int wave     = threadIdx.x >> 6;
    const int lane     = threadIdx.x & 63;
    const int n        = lane & 15;
    const int quad     = lane >> 4;
    const int rt_base  = rowgrp * 16 + wave * 4;

    bf16x8 Aa[4], Ab[4];
#pragma unroll
    for (int t = 0; t < 4; ++t) {
        Aa[t] = AfragA[(size_t)(rt_base + t) * 64 + lane];
        Ab[t] = AfragB[(size_t)(rt_base + t) * 64 + lane];
    }

    float bestv[4][4];
    int   bestc[4][4];
#pragma unroll
    for (int t = 0; t < 4; ++t)
#pragma unroll
        for (int r = 0; r < 4; ++r) { bestv[t][r] = -INFINITY; bestc[t][r] = 0; }

    const int ct0 = codepart * CT_PER_PART;
    size_t ib = (size_t)ct0 * 64;
    bf16x8 nb1  = Bhh[ib + lane];
    bf16x8 nb1s = Bhh[ib + (lane ^ 32)];
    bf16x8 nb3  = B31[ib + lane];

    for (int c = 0; c < CT_PER_PART; ++c) {
        bf16x8 b1 = nb1, b1s = nb1s, b3 = nb3;
        if (c + 1 < CT_PER_PART) {
            size_t ibn = (size_t)(ct0 + c + 1) * 64;
            nb1  = Bhh[ibn + lane];
            nb1s = Bhh[ibn + (lane ^ 32)];
            nb3  = B31[ibn + lane];
        }
#pragma unroll
        for (int t = 0; t < 4; ++t) {
            f32x4 s = __builtin_amdgcn_mfma_f32_16x16x32_bf16(
                          Aa[t], b1, (f32x4){0.f, 0.f, 0.f, 0.f}, 0, 0, 0);
            s = __builtin_amdgcn_mfma_f32_16x16x32_bf16(Aa[t], b1s, s, 0, 0, 0);
            s = __builtin_amdgcn_mfma_f32_16x16x32_bf16(Ab[t], b3,  s, 0, 0, 0);
#pragma unroll
            for (int r = 0; r < 4; ++r) {
                if (s[r] > bestv[t][r]) { bestv[t][r] = s[r]; bestc[t][r] = c; }
            }
        }
    }

    // reduce over the 16 code-class lanes, then device-scope max per row
#pragma unroll
    for (int t = 0; t < 4; ++t) {
#pragma unroll
        for (int r = 0; r < 4; ++r) {
            unsigned code = (unsigned)(codepart * (CT_PER_PART * 16) +
                                       bestc[t][r] * 16 + n);
            unsigned long long packed =
                ((unsigned long long)fkey(bestv[t][r]) << 32) |
                (unsigned long long)(0xFFFFFFFFu - code);
#pragma unroll
            for (int mk = 1; mk <= 8; mk <<= 1) {
                unsigned long long o = __shfl_xor(packed, mk, 64);
                packed = (o > packed) ? o : packed;
            }
            if (n == 0) {
                int row = (rt_base + t) * 16 + quad * 4 + r;
                atomicMax(&part[row], packed);
            }
        }
    }

    // __syncthreads drains vmcnt -> all this block's atomics are complete
    __syncthreads();
    if (threadIdx.x == 0)
        s_done = (atomicAdd(&cnt[rowgrp], 1u) == (unsigned)(CODEPARTS - 1));
    __syncthreads();

    if (s_done) {
        int row = rowgrp * 256 + threadIdx.x;
        unsigned long long v = atomicAdd(&part[row], 0ull);   // coherent read
        out[row] = (int)(0xFFFFFFFFu - (unsigned)(v & 0xFFFFFFFFull));
    }
}

extern "C" void kernel_launch(void* const* d_in, const int* in_sizes, int n_in,
                              void* d_out, int out_size, void* d_ws, size_t ws_size,
                              hipStream_t stream) {
    const float* x  = (const float*)d_in[0];   // [16384, 512]
    const float* P  = (const float*)d_in[1];   // [512, 16]
    const float* CB = (const float*)d_in[2];   // [8192, 16]
    int* out = (int*)d_out;                    // [16384] int32

    char* ws = (char*)d_ws;
    bf16x8* AfragA = (bf16x8*)(ws + WS_OFF_AFA);
    bf16x8* AfragB = (bf16x8*)(ws + WS_OFF_AFB);
    bf16x8* Bhh    = (bf16x8*)(ws + WS_OFF_BHH);
    bf16x8* B31    = (bf16x8*)(ws + WS_OFF_B31);
    unsigned long long* part = (unsigned long long*)(ws + WS_OFF_PART);
    unsigned* cnt  = (unsigned*)(ws + WS_OFF_CNT);
    bf16x8* Pf     = (bf16x8*)(ws + WS_OFF_PF);

    k_prep<<<PREP_BLOCKS, 256, 0, stream>>>(P, CB, Bhh, B31, Pf, part, cnt);
    k_proj<<<PROJ_BLOCKS, 256, 0, stream>>>(x, Pf, AfragA, AfragB);
    k_scan<<<N_ROWGRP * CODEPARTS, 256, 0, stream>>>(
        AfragA, AfragB, Bhh, B31, part, cnt, out);                 // 2048 blocks
}